// Round 1
// baseline (7674.214 us; speedup 1.0000x reference)
//
#include <hip/hip_runtime.h>
#include <math.h>

#define BATCH 16
#define CH 256
#define HH 64
#define WW 64
#define NEXP 4
#define EPSBN 1e-5f

constexpr int TCO = 8;    // output channels per block
constexpr int TH  = 32;   // output rows per block
constexpr int CCH = 4;    // input channels staged per LDS chunk
constexpr int HW  = HH * WW;                       // 4096
constexpr int K9  = 9;
constexpr int WPER = CH * K9;                      // 2304 weights per out-channel row
constexpr long long KERN_PER_B = (long long)CH * CH * K9;   // 2,359,296
constexpr long long Y_ELEMS = (long long)BATCH * CH * HH * WW;  // 16,777,216

// padded LDS row stride to break bank-conflict pattern (66 -> 67, odd)
constexpr int XP = WW + 3;   // 67

__device__ __forceinline__ float silu_(float v) {
    return v * (1.0f / (1.0f + expf(-v)));
}

// MODE 0: out = silu(bn(conv(in, wsrc)))              [conv1, shared weights]
// MODE 1: out = resid + silu(bn(conv(in, wsrc_b)))    [conv2, per-sample weights]
template<int MODE>
__global__ __launch_bounds__(256, 4)
void conv_kernel(const float* __restrict__ in,
                 const float* __restrict__ wsrc,
                 const float* __restrict__ bng, const float* __restrict__ bnb,
                 const float* __restrict__ bnm, const float* __restrict__ bnv,
                 const float* __restrict__ resid,
                 float* __restrict__ out)
{
    __shared__ float xtile[CCH][TH + 2][XP];   // 4*34*67*4 = 36448 B
    __shared__ float wtile[CCH][TCO][K9];      // 1152 B

    const int t   = threadIdx.x;
    const int cog = blockIdx.x;    // 0..31
    const int hg  = blockIdx.y;    // 0..1
    const int b   = blockIdx.z;    // 0..15
    const int co0 = cog * TCO;
    const int h0  = hg * TH;

    const int row = t >> 3;        // 0..31
    const int c0  = (t & 7) * 8;   // 0,8,..,56

    float acc[TCO][8];
    #pragma unroll
    for (int i = 0; i < TCO; ++i)
        #pragma unroll
        for (int p = 0; p < 8; ++p) acc[i][p] = 0.0f;

    const float* inb   = in + (long long)b * CH * HW;
    const float* wbase = (MODE == 0) ? wsrc : (wsrc + (long long)b * KERN_PER_B);

    for (int ci0 = 0; ci0 < CH; ci0 += CCH) {
        __syncthreads();
        // ---- stage input tile: CCH x 34 x 66 (stored with stride XP=67) ----
        for (int i = t; i < CCH * (TH + 2) * (WW + 2); i += 256) {
            int cc  = i / ((TH + 2) * (WW + 2));
            int rem = i % ((TH + 2) * (WW + 2));
            int r   = rem / (WW + 2);
            int c   = rem % (WW + 2);
            int gh  = h0 + r - 1;
            int gc  = c - 1;
            float v = 0.0f;
            if (gh >= 0 && gh < HH && gc >= 0 && gc < WW)
                v = inb[(long long)(ci0 + cc) * HW + gh * WW + gc];
            xtile[cc][r][c] = v;
        }
        // ---- stage weights: CCH*TCO*9 = 288 floats ----
        for (int i = t; i < CCH * TCO * K9; i += 256) {
            int cc  = i / (TCO * K9);
            int rem = i % (TCO * K9);
            int co  = rem / K9;
            int k   = rem % K9;
            wtile[cc][co][k] =
                wbase[(long long)(co0 + co) * WPER + (ci0 + cc) * K9 + k];
        }
        __syncthreads();

        #pragma unroll
        for (int cc = 0; cc < CCH; ++cc) {
            #pragma unroll
            for (int dh = 0; dh < 3; ++dh) {
                float xr[10];
                #pragma unroll
                for (int j = 0; j < 10; ++j)
                    xr[j] = xtile[cc][row + dh][c0 + j];
                #pragma unroll
                for (int co = 0; co < TCO; ++co) {
                    float w0 = wtile[cc][co][dh * 3 + 0];
                    float w1 = wtile[cc][co][dh * 3 + 1];
                    float w2 = wtile[cc][co][dh * 3 + 2];
                    #pragma unroll
                    for (int p = 0; p < 8; ++p)
                        acc[co][p] = fmaf(xr[p], w0,
                                     fmaf(xr[p + 1], w1,
                                     fmaf(xr[p + 2], w2, acc[co][p])));
                }
            }
        }
    }

    // ---- epilogue: BN + SiLU (+ residual), vectorized store ----
    #pragma unroll
    for (int co = 0; co < TCO; ++co) {
        int c = co0 + co;
        float sc = bng[c] * rsqrtf(bnv[c] + EPSBN);
        float sh = bnb[c] - bnm[c] * sc;
        long long base = ((long long)(b * CH + c) * HW) + (long long)(h0 + row) * WW + c0;
        float vals[8];
        if (MODE == 1) {
            const float4* r4 = reinterpret_cast<const float4*>(resid + base);
            float4 ra = r4[0], rb = r4[1];
            float rv[8] = {ra.x, ra.y, ra.z, ra.w, rb.x, rb.y, rb.z, rb.w};
            #pragma unroll
            for (int p = 0; p < 8; ++p)
                vals[p] = rv[p] + silu_(acc[co][p] * sc + sh);
        } else {
            #pragma unroll
            for (int p = 0; p < 8; ++p)
                vals[p] = silu_(acc[co][p] * sc + sh);
        }
        float4* o4 = reinterpret_cast<float4*>(out + base);
        o4[0] = make_float4(vals[0], vals[1], vals[2], vals[3]);
        o4[1] = make_float4(vals[4], vals[5], vals[6], vals[7]);
    }
}

// pooled[bc] = mean over HW of y[bc]
__global__ void pool_kernel(const float* __restrict__ y, float* __restrict__ pooled) {
    int bc = blockIdx.x;   // 0..B*C-1
    const float4* y4 = reinterpret_cast<const float4*>(y + (long long)bc * HW);
    int t = threadIdx.x;   // 256
    float s = 0.0f;
    #pragma unroll
    for (int k = 0; k < 4; ++k) {
        float4 v = y4[t + k * 256];
        s += v.x + v.y + v.z + v.w;
    }
    #pragma unroll
    for (int off = 32; off > 0; off >>= 1) s += __shfl_down(s, off, 64);
    __shared__ float wsum[4];
    int wid = t >> 6, lane = t & 63;
    if (lane == 0) wsum[wid] = s;
    __syncthreads();
    if (t == 0)
        pooled[bc] = (wsum[0] + wsum[1] + wsum[2] + wsum[3]) * (1.0f / HW);
}

// routing[b][e] = sigmoid(dot(pooled[b], wr[e]) + br[e])
__global__ void routing_kernel(const float* __restrict__ pooled,
                               const float* __restrict__ wr,
                               const float* __restrict__ br,
                               float* __restrict__ routing) {
    int t = threadIdx.x;
    if (t < BATCH * NEXP) {
        int b = t / NEXP, e = t % NEXP;
        float s = br[e];
        for (int c = 0; c < CH; ++c)
            s += pooled[b * CH + c] * wr[e * CH + c];
        routing[t] = 1.0f / (1.0f + expf(-s));
    }
}

// kern[b][j] = sum_e routing[b][e] * w_e[e][j]
__global__ void kern_gen(const float* __restrict__ w_e,
                         const float* __restrict__ routing,
                         float* __restrict__ kern) {
    int b = blockIdx.y;
    long long j = ((long long)blockIdx.x * 256 + threadIdx.x) * 4;
    float r0 = routing[b * NEXP + 0];
    float r1 = routing[b * NEXP + 1];
    float r2 = routing[b * NEXP + 2];
    float r3 = routing[b * NEXP + 3];
    float4 a = *reinterpret_cast<const float4*>(w_e + 0 * KERN_PER_B + j);
    float4 c = *reinterpret_cast<const float4*>(w_e + 1 * KERN_PER_B + j);
    float4 d = *reinterpret_cast<const float4*>(w_e + 2 * KERN_PER_B + j);
    float4 e = *reinterpret_cast<const float4*>(w_e + 3 * KERN_PER_B + j);
    float4 o;
    o.x = r0 * a.x + r1 * c.x + r2 * d.x + r3 * e.x;
    o.y = r0 * a.y + r1 * c.y + r2 * d.y + r3 * e.y;
    o.z = r0 * a.z + r1 * c.z + r2 * d.z + r3 * e.z;
    o.w = r0 * a.w + r1 * c.w + r2 * d.w + r3 * e.w;
    *reinterpret_cast<float4*>(kern + (long long)b * KERN_PER_B + j) = o;
}

extern "C" void kernel_launch(void* const* d_in, const int* in_sizes, int n_in,
                              void* d_out, int out_size, void* d_ws, size_t ws_size,
                              hipStream_t stream) {
    const float* x    = (const float*)d_in[0];
    const float* w1   = (const float*)d_in[1];
    const float* bn1g = (const float*)d_in[2];
    const float* bn1b = (const float*)d_in[3];
    const float* bn1m = (const float*)d_in[4];
    const float* bn1v = (const float*)d_in[5];
    const float* wr   = (const float*)d_in[6];
    const float* br   = (const float*)d_in[7];
    const float* w_e  = (const float*)d_in[8];
    const float* bn2g = (const float*)d_in[9];
    const float* bn2b = (const float*)d_in[10];
    const float* bn2m = (const float*)d_in[11];
    const float* bn2v = (const float*)d_in[12];
    float* out = (float*)d_out;

    float* ws      = (float*)d_ws;
    float* y       = ws;                         // 16,777,216 floats
    float* pooled  = y + Y_ELEMS;                // 4096
    float* routing = pooled + BATCH * CH;        // 64
    float* kern    = routing + BATCH * NEXP;     // 9,437,184

    dim3 cgrid(CH / TCO, HH / TH, BATCH);        // 32 x 2 x 16 = 1024 blocks

    conv_kernel<0><<<cgrid, 256, 0, stream>>>(x, w1, bn1g, bn1b, bn1m, bn1v,
                                              nullptr, y);
    pool_kernel<<<dim3(BATCH * CH), 256, 0, stream>>>(y, pooled);
    routing_kernel<<<dim3(1), 64, 0, stream>>>(pooled, wr, br, routing);
    kern_gen<<<dim3((int)(KERN_PER_B / 1024), BATCH), 256, 0, stream>>>(w_e, routing, kern);
    conv_kernel<1><<<cgrid, 256, 0, stream>>>(y, kern, bn2g, bn2b, bn2m, bn2v,
                                              x, out);
}

// Round 3
// 548.760 us; speedup vs baseline: 13.9847x; 13.9847x over previous
//
#include <hip/hip_runtime.h>
#include <math.h>

typedef _Float16 h16;
typedef _Float16 half8 __attribute__((ext_vector_type(8)));
typedef float f32x4 __attribute__((ext_vector_type(4)));

#define BATCH 16
#define CH 256
#define HH 64
#define WW 64
#define EPSBN 1e-5f

constexpr size_t WE_STRIDE = (size_t)CH * CH * 9;   // 589,824 elems per expert
// LDS input tile: 4 halo rows x 66 halo cols x 32 ci (padded to 40)
constexpr int CIP = 40;
constexpr int XT_ELEMS = 4 * 66 * CIP;   // 10560 halves = 21120 B

__device__ __forceinline__ float silu_(float v) {
    return v * (1.0f / (1.0f + __expf(-v)));
}

// Implicit-GEMM 3x3 conv, pad 1, via 9 tap-shifted GEMMs.
// MODE 0: in = x fp32 NCHW, wt = w1t [tap][co][ci] f16, out = y f16 NHWC, epilogue BN+SiLU
// MODE 1: in = y f16 NHWC, wt = wt2 [b][tap][co][ci] f16, out fp32 NCHW, resid+BN+SiLU
// MFMA contract (m89/m91): A[m=l15][k=quad*8+j], B[k=quad*8+j][n=l15], D[m=quad*4+r][n=l15]
template<int MODE>
__global__ __launch_bounds__(256, 3)
void conv_mfma(const void* __restrict__ inv,
               const h16* __restrict__ wt,
               const float* __restrict__ bng, const float* __restrict__ bnb,
               const float* __restrict__ bnm, const float* __restrict__ bnv,
               const float* __restrict__ resid,
               void* __restrict__ outv)
{
    __shared__ h16 xt[XT_ELEMS];

    const int t    = threadIdx.x;
    const int bx   = blockIdx.x;    // 32 spatial tiles (2 rows each)
    const int by   = blockIdx.y;    // 2 co tiles
    const int bz   = blockIdx.z;    // batch
    const int h0   = bx * 2;
    const int co0  = by * 128;
    const int wv   = t >> 6;
    const int lane = t & 63;
    const int quad = lane >> 4;
    const int l15  = lane & 15;
    const int mh   = wv >> 1, nh = wv & 1;
    const int spHalf = (MODE == 0) ? mh : nh;   // which 64-half of the 128-sp tile
    const int coHalf = (MODE == 0) ? nh : mh;   // which 64-half of the 128-co tile

    f32x4 acc[4][4];
    #pragma unroll
    for (int i = 0; i < 4; ++i)
        #pragma unroll
        for (int j = 0; j < 4; ++j) {
            f32x4 z = {0.f, 0.f, 0.f, 0.f};
            acc[i][j] = z;
        }

    // lane weight base: co = co0 + coHalf*64 + f*16 + l15 (f via +f*4096), ci = ci0 + quad*8
    const h16* wrow = wt + ((MODE == 1) ? (size_t)bz * 9 * 65536 : (size_t)0)
                         + ((size_t)(co0 + coHalf * 64 + l15) << 8)
                         + (size_t)(quad * 8);
    // LDS x-frag base: halo_sp = (spHalf+kh)*66 + f*16 + l15 + kw, ci = quad*8
    const int xbase = (spHalf * 66 + l15) * CIP + quad * 8;

    for (int ci0 = 0; ci0 < CH; ci0 += 32) {
        __syncthreads();
        if (MODE == 0) {
            // stage fp32 NCHW -> f16 LDS. tasks: 32ci x 4rows x 66cols = 8448
            const float* xin = (const float*)inv;
            for (int k = 0; k < 33; ++k) {
                int idx  = t + k * 256;
                int ci_i = idx / 264;
                int rem  = idx - ci_i * 264;
                int row  = rem / 66;
                int col  = rem - row * 66;
                int gh = h0 - 1 + row, gw = col - 1;
                float v = 0.f;
                if ((unsigned)gh < 64u && (unsigned)gw < 64u)
                    v = xin[((size_t)(bz * CH + ci0 + ci_i) << 12) + (gh << 6) + gw];
                xt[(row * 66 + col) * CIP + ci_i] = (h16)v;
            }
        } else {
            // stage f16 NHWC: 4rows x 66cols x 4 ci-octets = 1056 16B vector loads
            const h16* yin = (const h16*)inv;
            for (int k = 0; k < 5; ++k) {
                int idx = t + k * 256;
                if (idx < 1056) {
                    int cig = idx & 3;
                    int sp  = idx >> 2;
                    int row = sp / 66;
                    int col = sp - row * 66;
                    int gh = h0 - 1 + row, gw = col - 1;
                    half8 v = {0, 0, 0, 0, 0, 0, 0, 0};
                    if ((unsigned)gh < 64u && (unsigned)gw < 64u)
                        v = *(const half8*)(yin + (((size_t)(bz * 64 + gh) << 6) + gw) * 256
                                                + ci0 + cig * 8);
                    *(half8*)(xt + (row * 66 + col) * CIP + cig * 8) = v;
                }
            }
        }
        __syncthreads();

        const h16* wcol = wrow + ci0;
        #pragma unroll
        for (int kh = 0; kh < 3; ++kh)
        #pragma unroll
        for (int kw = 0; kw < 3; ++kw) {
            const int tap = kh * 3 + kw;
            half8 xf[4], wf[4];
            #pragma unroll
            for (int f = 0; f < 4; ++f) {
                xf[f] = *(const half8*)(xt + xbase + (kh * 66 + f * 16 + kw) * CIP);
                wf[f] = *(const half8*)(wcol + (size_t)tap * 65536 + f * 4096);
            }
            #pragma unroll
            for (int i = 0; i < 4; ++i)
                #pragma unroll
                for (int j = 0; j < 4; ++j) {
                    if (MODE == 0)
                        acc[i][j] = __builtin_amdgcn_mfma_f32_16x16x32_f16(
                            xf[i], wf[j], acc[i][j], 0, 0, 0);
                    else
                        acc[i][j] = __builtin_amdgcn_mfma_f32_16x16x32_f16(
                            wf[i], xf[j], acc[i][j], 0, 0, 0);
                }
        }
    }

    if (MODE == 0) {
        // D[sp][co] -> y f16 NHWC, BN+SiLU
        h16* yout = (h16*)outv;
        float sc[4], sh[4];
        #pragma unroll
        for (int j = 0; j < 4; ++j) {
            int c = co0 + coHalf * 64 + j * 16 + l15;
            float s = bng[c] * rsqrtf(bnv[c] + EPSBN);
            sc[j] = s; sh[j] = bnb[c] - bnm[c] * s;
        }
        #pragma unroll
        for (int i = 0; i < 4; ++i)
            #pragma unroll
            for (int r = 0; r < 4; ++r) {
                int spL = spHalf * 64 + i * 16 + quad * 4 + r;
                int h = h0 + (spL >> 6), w = spL & 63;
                size_t base = (((size_t)(bz * 64 + h) << 6) + w) * 256
                            + co0 + coHalf * 64 + l15;
                #pragma unroll
                for (int j = 0; j < 4; ++j) {
                    float v = acc[i][j][r] * sc[j] + sh[j];
                    yout[base + j * 16] = (h16)silu_(v);
                }
            }
    } else {
        // D[co][sp] -> out fp32 NCHW, resid + BN+SiLU
        float* outp = (float*)outv;
        #pragma unroll
        for (int i = 0; i < 4; ++i) {
            float sc[4], sh[4];
            #pragma unroll
            for (int r = 0; r < 4; ++r) {
                int c = co0 + coHalf * 64 + i * 16 + quad * 4 + r;
                float s = bng[c] * rsqrtf(bnv[c] + EPSBN);
                sc[r] = s; sh[r] = bnb[c] - bnm[c] * s;
            }
            #pragma unroll
            for (int j = 0; j < 4; ++j) {
                int spL = spHalf * 64 + j * 16 + l15;
                int h = h0 + (spL >> 6), w = spL & 63;
                #pragma unroll
                for (int r = 0; r < 4; ++r) {
                    int c = co0 + coHalf * 64 + i * 16 + quad * 4 + r;
                    size_t idx = ((size_t)(bz * CH + c) << 12) + (h << 6) + w;
                    float v = acc[i][j][r] * sc[r] + sh[r];
                    outp[idx] = resid[idx] + silu_(v);
                }
            }
        }
    }
}

// w1 [co][ci][9] fp32 -> w1t [tap][co][ci] f16
__global__ void prep_w1(const float* __restrict__ w1, h16* __restrict__ w1t) {
    int pair = blockIdx.x * 256 + threadIdx.x;   // co*256+ci
    #pragma unroll
    for (int tap = 0; tap < 9; ++tap)
        w1t[((size_t)tap << 16) + pair] = (h16)w1[(size_t)pair * 9 + tap];
}

// part[slice][b][c] = sum over 256 hw of y NHWC (no atomics)
__global__ void pool_kernel(const h16* __restrict__ y, float* __restrict__ part) {
    int slice = blockIdx.x;   // 16 hw slices of 256
    int b     = blockIdx.y;
    int c     = threadIdx.x;
    const h16* p = y + ((size_t)b * 4096 + slice * 256) * 256 + c;
    float s = 0.f;
    #pragma unroll 8
    for (int i = 0; i < 256; ++i) s += (float)p[(size_t)i * 256];
    part[((size_t)slice * BATCH + b) * 256 + c] = s;
}

__global__ void routing_kernel(const float* __restrict__ part,
                               const float* __restrict__ wr,
                               const float* __restrict__ br,
                               float* __restrict__ routing) {
    int t = threadIdx.x;
    if (t < 64) {
        int b = t >> 2, e = t & 3;
        float s = 0.f;
        for (int c = 0; c < 256; ++c) {
            float p = 0.f;
            for (int sl = 0; sl < 16; ++sl)
                p += part[((size_t)sl * BATCH + b) * 256 + c];
            s += p * wr[e * 256 + c];
        }
        s = s * (1.f / 4096.f) + br[e];
        routing[t] = 1.f / (1.f + __expf(-s));
    }
}

// wt2[b][tap][co][ci] f16 = sum_e routing[b][e] * w_e[e][(co*256+ci)*9+tap]
__global__ void kern_gen(const float* __restrict__ w_e,
                         const float* __restrict__ routing,
                         h16* __restrict__ wt2) {
    __shared__ float rsh[64];
    int t = threadIdx.x;
    if (t < 64) rsh[t] = routing[t];
    __syncthreads();
    int pair = blockIdx.x * 256 + t;   // co*256+ci
    float wv[4][9];
    #pragma unroll
    for (int e = 0; e < 4; ++e)
        #pragma unroll
        for (int k = 0; k < 9; ++k)
            wv[e][k] = w_e[(size_t)e * WE_STRIDE + (size_t)pair * 9 + k];
    for (int b = 0; b < 16; ++b) {
        float r0 = rsh[b * 4 + 0], r1 = rsh[b * 4 + 1];
        float r2 = rsh[b * 4 + 2], r3 = rsh[b * 4 + 3];
        #pragma unroll
        for (int tap = 0; tap < 9; ++tap) {
            float s = r0 * wv[0][tap] + r1 * wv[1][tap]
                    + r2 * wv[2][tap] + r3 * wv[3][tap];
            wt2[((size_t)(b * 9 + tap) << 16) + pair] = (h16)s;
        }
    }
}

extern "C" void kernel_launch(void* const* d_in, const int* in_sizes, int n_in,
                              void* d_out, int out_size, void* d_ws, size_t ws_size,
                              hipStream_t stream) {
    const float* x    = (const float*)d_in[0];
    const float* w1   = (const float*)d_in[1];
    const float* bn1g = (const float*)d_in[2];
    const float* bn1b = (const float*)d_in[3];
    const float* bn1m = (const float*)d_in[4];
    const float* bn1v = (const float*)d_in[5];
    const float* wr   = (const float*)d_in[6];
    const float* br   = (const float*)d_in[7];
    const float* w_e  = (const float*)d_in[8];
    const float* bn2g = (const float*)d_in[9];
    const float* bn2b = (const float*)d_in[10];
    const float* bn2m = (const float*)d_in[11];
    const float* bn2v = (const float*)d_in[12];

    char* w = (char*)d_ws;
    h16*   y       = (h16*)(w);                   // 33,554,432 B (f16 NHWC)
    h16*   w1t     = (h16*)(w + 33554432);        //  1,179,648 B
    h16*   wt2     = (h16*)(w + 34734080);        // 18,874,368 B
    float* part    = (float*)(w + 53608448);      //    262,144 B
    float* routing = (float*)(w + 53870592);      //        256 B

    prep_w1<<<dim3(256), 256, 0, stream>>>(w1, w1t);

    dim3 cgrid(32, 2, BATCH);   // sp-tiles x co-tiles x batch
    conv_mfma<0><<<cgrid, 256, 0, stream>>>(x, w1t, bn1g, bn1b, bn1m, bn1v,
                                            nullptr, y);
    pool_kernel<<<dim3(16, BATCH), 256, 0, stream>>>(y, part);
    routing_kernel<<<dim3(1), 64, 0, stream>>>(part, wr, br, routing);
    kern_gen<<<dim3(256), 256, 0, stream>>>(w_e, routing, wt2);
    conv_mfma<1><<<cgrid, 256, 0, stream>>>(y, wt2, bn2g, bn2b, bn2m, bn2v,
                                            x, (float*)d_out);
}

// Round 4
// 479.880 us; speedup vs baseline: 15.9919x; 1.1435x over previous
//
#include <hip/hip_runtime.h>
#include <math.h>

typedef _Float16 h16;
typedef _Float16 half8 __attribute__((ext_vector_type(8)));
typedef float f32x4 __attribute__((ext_vector_type(4)));

#define BATCH 16
#define CH 256
#define EPSBN 1e-5f

constexpr size_t WE_STRIDE = (size_t)CH * CH * 9;   // 589,824 elems per expert
constexpr int REG = 2120;   // halves per ci-octet region: 265 sp slots * 8 (pad slot kills bank overlap)

__device__ __forceinline__ float silu_(float v) {
    return v * (1.0f / (1.0f + __expf(-v)));
}

// Implicit-GEMM 3x3 conv (pad 1) over NHWC f16 input, 9 tap-shifted GEMMs.
// Tile: 128 sp (2 rows) x 128 co. 4 waves, each owns a distinct 32-co slice
// (halves redundant weight loads). BK=32 ci per LDS chunk.
// MFMA contract (m89/m91): A[m=l15][k=quad*8+j], B[k=quad*8+j][n=l15], D[m=quad*4+r][n=l15]
// MODE 0: out = y f16 NHWC, BN+SiLU.       acc[i*2+j]: i=sp frag(8), j=co frag(2)
// MODE 1: out fp32 NCHW, resid+BN+SiLU.    acc[i*8+j]: i=co frag(2), j=sp frag(8)
template<int MODE>
__global__ __launch_bounds__(256, 3)
void conv_mfma(const h16* __restrict__ xin,
               const h16* __restrict__ wt,
               const float* __restrict__ bng, const float* __restrict__ bnb,
               const float* __restrict__ bnm, const float* __restrict__ bnv,
               const float* __restrict__ resid,
               void* __restrict__ outv)
{
    __shared__ h16 xt[4 * REG];   // 16,960 B

    const int t    = threadIdx.x;
    const int bx   = blockIdx.x;    // 32 spatial tiles (2 rows each)
    const int by   = blockIdx.y;    // 2 co tiles
    const int bz   = blockIdx.z;    // batch
    const int h0   = bx * 2;
    const int co0  = by * 128;
    const int wv   = t >> 6;        // wave owns co slice wv*32
    const int lane = t & 63;
    const int quad = lane >> 4;
    const int l15  = lane & 15;

    f32x4 acc[16];
    #pragma unroll
    for (int i = 0; i < 16; ++i) {
        f32x4 z = {0.f, 0.f, 0.f, 0.f};
        acc[i] = z;
    }

    // lane weight base: co = co0 + wv*32 + f*16 + l15, ci = ci0 + quad*8
    const h16* wrow = wt + ((MODE == 1) ? (size_t)bz * 9 * 65536 : (size_t)0)
                         + ((size_t)(co0 + wv * 32 + l15) << 8)
                         + (size_t)(quad * 8);
    // per-lane LDS base; all frag reads are compile-time offsets from this
    const h16* xlane = xt + quad * REG + l15 * 8;

    for (int ci0 = 0; ci0 < CH; ci0 += 32) {
        __syncthreads();
        // stage 4 halo rows x 66 halo cols x 32 ci: 1056 half8 tasks, cig-minor
        // (4 consecutive threads -> 64 B contiguous global)
        #pragma unroll
        for (int k = 0; k < 5; ++k) {
            int idx = t + k * 256;
            if (idx < 1056) {
                int cig = idx & 3;
                int sp  = idx >> 2;            // row*66+col, 0..263
                int row = sp / 66;
                int col = sp - row * 66;
                int gh = h0 - 1 + row, gw = col - 1;
                half8 v = {0, 0, 0, 0, 0, 0, 0, 0};
                if ((unsigned)gh < 64u && (unsigned)gw < 64u)
                    v = *(const half8*)(xin + (((size_t)(bz * 64 + gh) << 6) + gw) * 256
                                            + ci0 + cig * 8);
                *(half8*)(xt + cig * REG + sp * 8) = v;
            }
        }
        __syncthreads();

        const h16* wc = wrow + ci0;
        #pragma unroll
        for (int kh = 0; kh < 3; ++kh)
        #pragma unroll
        for (int kw = 0; kw < 3; ++kw) {
            const int tap = kh * 3 + kw;
            half8 wf[2], xf[8];
            #pragma unroll
            for (int f = 0; f < 2; ++f)
                wf[f] = *(const half8*)(wc + (size_t)tap * 65536 + f * 4096);
            #pragma unroll
            for (int i = 0; i < 8; ++i)
                xf[i] = *(const half8*)(xlane + ((kh + (i >> 2)) * 66 + (i & 3) * 16 + kw) * 8);
            if (MODE == 0) {
                #pragma unroll
                for (int i = 0; i < 8; ++i)
                    #pragma unroll
                    for (int j = 0; j < 2; ++j)
                        acc[i * 2 + j] = __builtin_amdgcn_mfma_f32_16x16x32_f16(
                            xf[i], wf[j], acc[i * 2 + j], 0, 0, 0);
            } else {
                #pragma unroll
                for (int i = 0; i < 2; ++i)
                    #pragma unroll
                    for (int j = 0; j < 8; ++j)
                        acc[i * 8 + j] = __builtin_amdgcn_mfma_f32_16x16x32_f16(
                            wf[i], xf[j], acc[i * 8 + j], 0, 0, 0);
            }
        }
    }

    if (MODE == 0) {
        // D[sp][co] -> y f16 NHWC, BN+SiLU
        h16* yout = (h16*)outv;
        float sc[2], sh[2];
        #pragma unroll
        for (int j = 0; j < 2; ++j) {
            int c = co0 + wv * 32 + j * 16 + l15;
            float s = bng[c] * rsqrtf(bnv[c] + EPSBN);
            sc[j] = s; sh[j] = bnb[c] - bnm[c] * s;
        }
        #pragma unroll
        for (int i = 0; i < 8; ++i)
            #pragma unroll
            for (int r = 0; r < 4; ++r) {
                int spL = i * 16 + quad * 4 + r;
                int h = h0 + (spL >> 6), w = spL & 63;
                size_t base = (((size_t)(bz * 64 + h) << 6) + w) * 256
                            + co0 + wv * 32 + l15;
                #pragma unroll
                for (int j = 0; j < 2; ++j) {
                    float v = acc[i * 2 + j][r] * sc[j] + sh[j];
                    yout[base + j * 16] = (h16)silu_(v);
                }
            }
    } else {
        // D[co][sp] -> out fp32 NCHW, resid + BN+SiLU
        float* outp = (float*)outv;
        #pragma unroll
        for (int i = 0; i < 2; ++i) {
            float sc[4], sh[4];
            #pragma unroll
            for (int r = 0; r < 4; ++r) {
                int c = co0 + wv * 32 + i * 16 + quad * 4 + r;
                float s = bng[c] * rsqrtf(bnv[c] + EPSBN);
                sc[r] = s; sh[r] = bnb[c] - bnm[c] * s;
            }
            #pragma unroll
            for (int j = 0; j < 8; ++j) {
                int spL = j * 16 + l15;
                int h = h0 + (spL >> 6), w = spL & 63;
                #pragma unroll
                for (int r = 0; r < 4; ++r) {
                    int c = co0 + wv * 32 + i * 16 + quad * 4 + r;
                    size_t idx = ((size_t)(bz * CH + c) << 12) + (h << 6) + w;
                    float v = acc[i * 8 + j][r] * sc[r] + sh[r];
                    outp[idx] = resid[idx] + silu_(v);
                }
            }
        }
    }
}

// x fp32 NCHW -> xh f16 NHWC (LDS-tiled transpose). Block = (cg 64-ch group, h, b).
__global__ __launch_bounds__(256)
void prep_x(const float* __restrict__ x, h16* __restrict__ xh) {
    __shared__ float lt[64][65];
    int cg = blockIdx.x, h = blockIdx.y, b = blockIdx.z;
    int t = threadIdx.x;
    {
        int cl = t >> 2, wq = t & 3;
        const float4* src = (const float4*)(x + (((size_t)(b * CH + cg * 64 + cl)) << 12)
                                              + ((size_t)h << 6));
        #pragma unroll
        for (int k = 0; k < 4; ++k) {
            int w4 = wq + k * 4;
            float4 v = src[w4];
            lt[cl][w4 * 4 + 0] = v.x;
            lt[cl][w4 * 4 + 1] = v.y;
            lt[cl][w4 * 4 + 2] = v.z;
            lt[cl][w4 * 4 + 3] = v.w;
        }
    }
    __syncthreads();
    {
        int wl = t >> 2, cq = t & 3;
        half8 a2[2];
        h16* ap = (h16*)a2;
        #pragma unroll
        for (int m = 0; m < 16; ++m) ap[m] = (h16)lt[cq * 16 + m][wl];
        size_t base = ((((size_t)(b * 64 + h)) << 6) + wl) * 256 + cg * 64 + cq * 16;
        *(half8*)(xh + base)     = a2[0];
        *(half8*)(xh + base + 8) = a2[1];
    }
}

// w1 [co][ci][9] fp32 -> w1t [tap][co][ci] f16
__global__ void prep_w1(const float* __restrict__ w1, h16* __restrict__ w1t) {
    int pair = blockIdx.x * 256 + threadIdx.x;   // co*256+ci
    #pragma unroll
    for (int tap = 0; tap < 9; ++tap)
        w1t[((size_t)tap << 16) + pair] = (h16)w1[(size_t)pair * 9 + tap];
}

// part[slice][b][c] = partial sum over 256 sp of y NHWC (vectorized, no atomics)
__global__ __launch_bounds__(256)
void pool_kernel(const h16* __restrict__ y, float* __restrict__ part) {
    __shared__ float red[8][256];
    int slice = blockIdx.x, b = blockIdx.y;
    int t = threadIdx.x;
    int oct = t & 31, ss = t >> 5;
    float a[8];
    #pragma unroll
    for (int k = 0; k < 8; ++k) a[k] = 0.f;
    const h16* p = y + ((size_t)(b * 4096 + slice * 256 + ss)) * 256 + oct * 8;
    #pragma unroll 4
    for (int i = 0; i < 32; ++i) {
        half8 v = *(const half8*)(p + (size_t)i * 8 * 256);
        #pragma unroll
        for (int k = 0; k < 8; ++k) a[k] += (float)v[k];
    }
    #pragma unroll
    for (int k = 0; k < 8; ++k) red[ss][oct * 8 + k] = a[k];
    __syncthreads();
    float s = 0.f;
    #pragma unroll
    for (int q = 0; q < 8; ++q) s += red[q][t];
    part[((size_t)slice * BATCH + b) * 256 + t] = s;
}

__global__ void routing_kernel(const float* __restrict__ part,
                               const float* __restrict__ wr,
                               const float* __restrict__ br,
                               float* __restrict__ routing) {
    int t = threadIdx.x;
    if (t < 64) {
        int b = t >> 2, e = t & 3;
        float s = 0.f;
        for (int c = 0; c < 256; ++c) {
            float p = 0.f;
            for (int sl = 0; sl < 16; ++sl)
                p += part[((size_t)sl * BATCH + b) * 256 + c];
            s += p * wr[e * 256 + c];
        }
        s = s * (1.f / 4096.f) + br[e];
        routing[t] = 1.f / (1.f + __expf(-s));
    }
}

// wt2[b][tap][co][ci] f16 = sum_e routing[b][e] * w_e[e][(co*256+ci)*9+tap]
// w_e staged through LDS so global reads are float4-coalesced.
__global__ __launch_bounds__(256)
void kern_gen(const float* __restrict__ w_e,
              const float* __restrict__ routing,
              h16* __restrict__ wt2) {
    __shared__ float lw[4 * 2304];   // 36,864 B
    __shared__ float rsh[64];
    int t = threadIdx.x;
    int pair0 = blockIdx.x * 256;
    if (t < 64) rsh[t] = routing[t];
    #pragma unroll
    for (int e = 0; e < 4; ++e) {
        const float4* src = (const float4*)(w_e + (size_t)e * WE_STRIDE + (size_t)pair0 * 9);
        #pragma unroll
        for (int k = 0; k < 3; ++k) {
            int idx = t + k * 256;
            if (idx < 576) {
                float4 v = src[idx];
                float* d = &lw[e * 2304 + idx * 4];
                d[0] = v.x; d[1] = v.y; d[2] = v.z; d[3] = v.w;
            }
        }
    }
    __syncthreads();
    float wv[4][9];
    #pragma unroll
    for (int e = 0; e < 4; ++e)
        #pragma unroll
        for (int k = 0; k < 9; ++k)
            wv[e][k] = lw[e * 2304 + t * 9 + k];
    for (int b = 0; b < 16; ++b) {
        float r0 = rsh[b * 4 + 0], r1 = rsh[b * 4 + 1];
        float r2 = rsh[b * 4 + 2], r3 = rsh[b * 4 + 3];
        #pragma unroll
        for (int tap = 0; tap < 9; ++tap) {
            float s = r0 * wv[0][tap] + r1 * wv[1][tap]
                    + r2 * wv[2][tap] + r3 * wv[3][tap];
            wt2[((size_t)(b * 9 + tap) << 16) + pair0 + t] = (h16)s;
        }
    }
}

extern "C" void kernel_launch(void* const* d_in, const int* in_sizes, int n_in,
                              void* d_out, int out_size, void* d_ws, size_t ws_size,
                              hipStream_t stream) {
    const float* x    = (const float*)d_in[0];
    const float* w1   = (const float*)d_in[1];
    const float* bn1g = (const float*)d_in[2];
    const float* bn1b = (const float*)d_in[3];
    const float* bn1m = (const float*)d_in[4];
    const float* bn1v = (const float*)d_in[5];
    const float* wr   = (const float*)d_in[6];
    const float* br   = (const float*)d_in[7];
    const float* w_e  = (const float*)d_in[8];
    const float* bn2g = (const float*)d_in[9];
    const float* bn2b = (const float*)d_in[10];
    const float* bn2m = (const float*)d_in[11];
    const float* bn2v = (const float*)d_in[12];

    char* w = (char*)d_ws;
    h16*   xh      = (h16*)(w);                   // 33,554,432 B (x as f16 NHWC)
    h16*   y       = (h16*)(w + 33554432);        // 33,554,432 B (f16 NHWC)
    h16*   w1t     = (h16*)(w + 67108864);        //  1,179,648 B
    h16*   wt2     = (h16*)(w + 68288512);        // 18,874,368 B
    float* part    = (float*)(w + 87162880);      //    262,144 B
    float* routing = (float*)(w + 87425024);      //        256 B

    prep_x<<<dim3(4, 64, BATCH), 256, 0, stream>>>(x, xh);
    prep_w1<<<dim3(256), 256, 0, stream>>>(w1, w1t);

    dim3 cgrid(32, 2, BATCH);   // sp-tiles x co-tiles x batch
    conv_mfma<0><<<cgrid, 256, 0, stream>>>(xh, w1t, bn1g, bn1b, bn1m, bn1v,
                                            nullptr, y);
    pool_kernel<<<dim3(16, BATCH), 256, 0, stream>>>(y, part);
    routing_kernel<<<dim3(1), 64, 0, stream>>>(part, wr, br, routing);
    kern_gen<<<dim3(256), 256, 0, stream>>>(w_e, routing, wt2);
    conv_mfma<1><<<cgrid, 256, 0, stream>>>(y, wt2, bn2g, bn2b, bn2m, bn2v,
                                            x, (float*)d_out);
}